// Round 1
// baseline (113.439 us; speedup 1.0000x reference)
//
#include <hip/hip_runtime.h>
#include <hip/hip_bf16.h>

#define BB 4
#define CC 256
#define HH 64
#define WW 64
#define OO 256
#define NK2 9
#define HWP (HH*WW)      // 4096
#define KD (NK2*CC)      // 2304

typedef __bf16 bf16x8 __attribute__((ext_vector_type(8)));
typedef float f32x4 __attribute__((ext_vector_type(4)));
typedef unsigned short u16x8 __attribute__((ext_vector_type(8)));

static __device__ __forceinline__ float bf2f(unsigned short v) {
  return __uint_as_float(((unsigned)v) << 16);
}
static __device__ __forceinline__ unsigned short f2bf(float f) {
  __hip_bfloat16 h = __float2bfloat16(f);
  return __builtin_bit_cast(unsigned short, h);
}

// x [B][C][H][W] fp32  ->  xt [B][H][W][C] bf16
__global__ void k_xpose(const float* __restrict__ x, unsigned short* __restrict__ xt) {
  __shared__ float tile[32][33];
  int b  = blockIdx.z;
  int c0 = blockIdx.y * 32;
  int p0 = blockIdx.x * 32;                 // hw tile base
  int tx = threadIdx.x & 31;
  int ty = threadIdx.x >> 5;                // 0..7
  const float* src = x + ((size_t)b * CC + c0) * HWP + p0;
#pragma unroll
  for (int i = 0; i < 4; ++i)
    tile[ty + i * 8][tx] = src[(size_t)(ty + i * 8) * HWP + tx];
  __syncthreads();
  unsigned short* dst = xt + ((size_t)b * HWP + p0) * CC + c0;
#pragma unroll
  for (int i = 0; i < 4; ++i) {
    float v = tile[tx][ty + i * 8];
    dst[(size_t)(ty + i * 8) * CC + tx] = f2bf(v);
  }
}

// weight [O][C][3][3] fp32 -> wt [O][kpt][C] bf16
__global__ void k_wt(const float* __restrict__ w, unsigned short* __restrict__ wt) {
  int i = blockIdx.x * 256 + threadIdx.x;
  if (i >= OO * KD) return;
  int o = i / KD;
  int r = i - o * KD;
  int kpt = r >> 8;       // /256
  int c = r & 255;
  wt[i] = f2bf(w[((size_t)o * CC + c) * NK2 + kpt]);
}

// Implicit GEMM: per block, 32 output locations x all 256 output channels.
__launch_bounds__(256)
__global__ void k_dcn(const unsigned short* __restrict__ xt,
                      const unsigned short* __restrict__ wt,
                      const float* __restrict__ sp,
                      float* __restrict__ out) {
  // sampled panel [32 m][256 c] bf16, XOR-swizzled
  __shared__ __align__(16) unsigned short Alds[32 * 256];

  const int tid = threadIdx.x;
  const int m0 = blockIdx.x * 32;
  const int b = m0 >> 12;
  const int rem = m0 & 4095;
  const int y = rem >> 6;
  const int x0 = rem & 63;                  // 0 or 32

  // sampling mapping: 8 threads per location, 32 channels each
  const int sm = tid >> 3;                  // 0..31 location in tile
  const int cc8 = (tid & 7) * 32;           // channel base
  const int gx = x0 + sm;

  // mfma mapping
  const int wv = tid >> 6;                  // wave 0..3
  const int lane = tid & 63;
  const int l15 = lane & 15;
  const int lg = lane >> 4;                 // 0..3
  const int obase = wv * 64;

  f32x4 acc[4][2];
#pragma unroll
  for (int i = 0; i < 4; ++i)
#pragma unroll
    for (int j = 0; j < 2; ++j)
      acc[i][j] = (f32x4){0.f, 0.f, 0.f, 0.f};

  // weight row base pointers (per wave), kpt offset added in loop
  const unsigned short* wbase[4];
#pragma unroll
  for (int fm = 0; fm < 4; ++fm) {
    int o = obase + fm * 16 + l15;
    wbase[fm] = wt + (size_t)o * KD + 8 * lg;
  }

  char* Ab = (char*)Alds;
  const unsigned short* xb = xt + (size_t)b * HWP * CC + cc8;

  for (int kpt = 0; kpt < NK2; ++kpt) {
    // ---- build sampled panel in LDS ----
    {
      float offY = sp[((size_t)b * 18 + 2 * kpt) * HWP + y * WW + gx];
      float offX = sp[((size_t)b * 18 + 2 * kpt + 1) * HWP + y * WW + gx];
      float py = (float)y + offY;
      float px = (float)gx + offX;
      float fy = floorf(py), fx = floorf(px);
      float ly = py - fy, lx = px - fx;
      int y0i = (int)fy, x0i = (int)fx;
      int y1i = y0i + 1, x1i = x0i + 1;
      bool vy0 = (y0i >= 0) & (y0i < HH);
      bool vy1 = (y1i >= 0) & (y1i < HH);
      bool vx0 = (x0i >= 0) & (x0i < WW);
      bool vx1 = (x1i >= 0) & (x1i < WW);
      float w00 = (1.f - ly) * (1.f - lx);
      float w01 = (1.f - ly) * lx;
      float w10 = ly * (1.f - lx);
      float w11 = ly * lx;
      w00 = (vy0 && vx0) ? w00 : 0.f;
      w01 = (vy0 && vx1) ? w01 : 0.f;
      w10 = (vy1 && vx0) ? w10 : 0.f;
      w11 = (vy1 && vx1) ? w11 : 0.f;
      int yc0 = min(max(y0i, 0), HH - 1), yc1 = min(max(y1i, 0), HH - 1);
      int xc0 = min(max(x0i, 0), WW - 1), xc1 = min(max(x1i, 0), WW - 1);
      const unsigned short* p00 = xb + (yc0 * WW + xc0) * CC;
      const unsigned short* p01 = xb + (yc0 * WW + xc1) * CC;
      const unsigned short* p10 = xb + (yc1 * WW + xc0) * CC;
      const unsigned short* p11 = xb + (yc1 * WW + xc1) * CC;
#pragma unroll
      for (int cg = 0; cg < 4; ++cg) {
        u16x8 a00 = *reinterpret_cast<const u16x8*>(p00 + cg * 8);
        u16x8 a01 = *reinterpret_cast<const u16x8*>(p01 + cg * 8);
        u16x8 a10 = *reinterpret_cast<const u16x8*>(p10 + cg * 8);
        u16x8 a11 = *reinterpret_cast<const u16x8*>(p11 + cg * 8);
        u16x8 r;
#pragma unroll
        for (int j = 0; j < 8; ++j) {
          float s = fmaf(w11, bf2f(a11[j]),
                    fmaf(w10, bf2f(a10[j]),
                    fmaf(w01, bf2f(a01[j]), w00 * bf2f(a00[j]))));
          r[j] = f2bf(s);
        }
        unsigned bo = (unsigned)(sm * 512 + (cc8 + cg * 8) * 2) ^ (unsigned)((sm & 7) << 4);
        *reinterpret_cast<u16x8*>(Ab + bo) = r;
      }
    }
    __syncthreads();

    // ---- MFMA over this kernel point: K = 256 channels, 8 chunks of 32 ----
#pragma unroll
    for (int kk = 0; kk < 8; ++kk) {
      bf16x8 afr[4];
      bf16x8 bfr[2];
#pragma unroll
      for (int fm = 0; fm < 4; ++fm)
        afr[fm] = __builtin_bit_cast(bf16x8,
            *reinterpret_cast<const u16x8*>(wbase[fm] + (size_t)kpt * CC + kk * 32));
#pragma unroll
      for (int fn = 0; fn < 2; ++fn) {
        int mr = fn * 16 + l15;
        unsigned bo = (unsigned)(mr * 512 + kk * 64 + lg * 16) ^ (unsigned)((mr & 7) << 4);
        bfr[fn] = __builtin_bit_cast(bf16x8, *reinterpret_cast<const u16x8*>(Ab + bo));
      }
#pragma unroll
      for (int fm = 0; fm < 4; ++fm)
#pragma unroll
        for (int fn = 0; fn < 2; ++fn)
          acc[fm][fn] = __builtin_amdgcn_mfma_f32_16x16x32_bf16(afr[fm], bfr[fn], acc[fm][fn], 0, 0, 0);
    }
    __syncthreads();
  }

  // ---- epilogue: relu + store (C/D: col=lane&15 -> m, row=4*(lane>>4)+r -> o) ----
#pragma unroll
  for (int fm = 0; fm < 4; ++fm) {
#pragma unroll
    for (int fn = 0; fn < 2; ++fn) {
#pragma unroll
      for (int r = 0; r < 4; ++r) {
        int o = obase + fm * 16 + lg * 4 + r;
        int xm = x0 + fn * 16 + l15;
        out[(((size_t)b * OO + o) * HH + y) * WW + xm] = fmaxf(acc[fm][fn][r], 0.0f);
      }
    }
  }
}

extern "C" void kernel_launch(void* const* d_in, const int* in_sizes, int n_in,
                              void* d_out, int out_size, void* d_ws, size_t ws_size,
                              hipStream_t stream) {
  const float* x = (const float*)d_in[0];
  const float* sp = (const float*)d_in[1];
  const float* w = (const float*)d_in[2];
  float* out = (float*)d_out;

  unsigned short* xt = (unsigned short*)d_ws;                              // 8,388,608 B
  unsigned short* wt = (unsigned short*)((char*)d_ws + (size_t)8388608);   // 1,179,648 B

  k_xpose<<<dim3(HWP / 32, CC / 32, BB), 256, 0, stream>>>(x, xt);
  k_wt<<<(OO * KD + 255) / 256, 256, 0, stream>>>(w, wt);
  k_dcn<<<dim3(BB * HWP / 32), 256, 0, stream>>>(xt, wt, sp, out);
}